// Round 5
// baseline (246.960 us; speedup 1.0000x reference)
//
#include <hip/hip_runtime.h>
#include <math.h>

typedef __bf16 bf16x8 __attribute__((ext_vector_type(8)));
typedef unsigned short u16x8 __attribute__((ext_vector_type(8)));
typedef float f32x4 __attribute__((ext_vector_type(4)));

namespace {
constexpr int kB   = 32;
constexpr int kC   = 64;
constexpr int kT   = 8192;
constexpr int kOUT = 129;
constexpr int kKK  = 1024;   // K*K
constexpr int kNKC = 8;      // k-chunks in phase GEMM (128 f each)
}

__device__ inline float sin2pi(float r) {  // r in revolutions, [0,1)
  float o; asm("v_sin_f32 %0, %1" : "=v"(o) : "v"(r)); return o;
}
__device__ inline float cos2pi(float r) {
  float o; asm("v_cos_f32 %0, %1" : "=v"(o) : "v"(r)); return o;
}
__device__ inline unsigned short f2bf_rne(float f) {
  unsigned int u = __builtin_bit_cast(unsigned int, f);
  return (unsigned short)((u + 0x7fffu + ((u >> 16) & 1u)) >> 16);
}
__device__ inline float bf2f(unsigned short h) {
  return __builtin_bit_cast(float, (unsigned int)h << 16);
}
__device__ inline void split8(const float* v, bf16x8& hi, bf16x8& lo) {
  u16x8 h, l;
#pragma unroll
  for (int j = 0; j < 8; ++j) {
    const unsigned short hh = f2bf_rne(v[j]);
    h[j] = hh;
    l[j] = f2bf_rne(v[j] - bf2f(hh));
  }
  hi = __builtin_bit_cast(bf16x8, h);
  lo = __builtin_bit_cast(bf16x8, l);
}

// ---------------------------------------------------------------------------
// Kernel 1: a_part[kc][b][o][c] = sum_{f in kc-chunk} z[o,f]*cis[f,c] via
// bf16 MFMA (split hi/lo on both operands; drop lo*lo). No LDS: cis computed
// in-register (B-frag), z loaded per-lane (A-frag). Grid = 32b x 8kc x 2mh
// = 512 blocks x 256 thr; wave w owns col-tile c = w*16+..; mh splits the 9
// M-tiles 5/4. MFMA maps (verified r4): A row=lane&15, k=8*(lane>>4)+j;
// B col=lane&15, same k; D col=lane&15, row=(lane>>4)*4+r.
// ---------------------------------------------------------------------------
__global__ __launch_bounds__(256) void sa_phase_mfma(
    const float* __restrict__ positions,
    const float* __restrict__ z_real,
    const float* __restrict__ z_imag,
    float* __restrict__ part)
{
  const int bid = blockIdx.x;
  const int b   = bid & 31;
  const int kc  = (bid >> 5) & 7;
  const int mh  = bid >> 8;            // 0: m-tiles 0..4, 1: m-tiles 5..8
  const int w    = threadIdx.x >> 6;
  const int lane = threadIdx.x & 63;
  const int cg   = lane >> 4;
  const int cl   = lane & 15;
  const int c    = w * 16 + cl;
  const int f0   = kc * 128;

  const float2 p = reinterpret_cast<const float2*>(positions)[b * kC + c];

  // B-frags: cis for 4 k-steps of 32, split bf16
  bf16x8 BcH[4], BcL[4], BsH[4], BsL[4];
#pragma unroll
  for (int ks = 0; ks < 4; ++ks) {
    float cs[8], sn[8];
#pragma unroll
    for (int j = 0; j < 8; ++j) {
      const int f = f0 + ks * 32 + 8 * cg + j;
      const float kf = (float)((f & 31) + 1);   // coef_k = (f % 32) + 1
      const float lf = (float)((f >> 5) + 1);   // coef_l = (f / 32) + 1
      // match reference: fl(fl(x*k) + fl(y*l)); trig on fract (revolutions)
      const float wv = __fadd_rn(__fmul_rn(p.x, kf), __fmul_rn(p.y, lf));
      const float r  = wv - floorf(wv);
      cs[j] = cos2pi(r);
      sn[j] = sin2pi(r);
    }
    split8(cs, BcH[ks], BcL[ks]);
    split8(sn, BsH[ks], BsL[ks]);
  }

  const int nm  = mh ? 4 : 5;
  const int ob0 = mh * 80;

#pragma unroll
  for (int m = 0; m < 5; ++m) {
    if (m < nm) {
      const int ob = ob0 + m * 16;
      const int oa = ob + cl;          // A-row this lane loads
      bf16x8 ArH[4], ArL[4], AiH[4], AiL[4];
      if (oa < kOUT) {
        const float* zr = z_real + (size_t)oa * kKK + f0 + 8 * cg;
        const float* zi = z_imag + (size_t)oa * kKK + f0 + 8 * cg;
#pragma unroll
        for (int ks = 0; ks < 4; ++ks) {
          float vr[8], vi[8];
          *reinterpret_cast<float4*>(vr)     = *reinterpret_cast<const float4*>(zr + ks * 32);
          *reinterpret_cast<float4*>(vr + 4) = *reinterpret_cast<const float4*>(zr + ks * 32 + 4);
          *reinterpret_cast<float4*>(vi)     = *reinterpret_cast<const float4*>(zi + ks * 32);
          *reinterpret_cast<float4*>(vi + 4) = *reinterpret_cast<const float4*>(zi + ks * 32 + 4);
          split8(vr, ArH[ks], ArL[ks]);
          split8(vi, AiH[ks], AiL[ks]);
        }
      } else {
#pragma unroll
        for (int ks = 0; ks < 4; ++ks) {
          u16x8 z0 = {0,0,0,0,0,0,0,0};
          ArH[ks] = ArL[ks] = AiH[ks] = AiL[ks] = __builtin_bit_cast(bf16x8, z0);
        }
      }

      f32x4 acc = {0.f, 0.f, 0.f, 0.f};
#pragma unroll
      for (int ks = 0; ks < 4; ++ks) {
        acc = __builtin_amdgcn_mfma_f32_16x16x32_bf16(ArH[ks], BcH[ks], acc, 0, 0, 0);
        acc = __builtin_amdgcn_mfma_f32_16x16x32_bf16(ArH[ks], BcL[ks], acc, 0, 0, 0);
        acc = __builtin_amdgcn_mfma_f32_16x16x32_bf16(ArL[ks], BcH[ks], acc, 0, 0, 0);
        acc = __builtin_amdgcn_mfma_f32_16x16x32_bf16(AiH[ks], BsH[ks], acc, 0, 0, 0);
        acc = __builtin_amdgcn_mfma_f32_16x16x32_bf16(AiH[ks], BsL[ks], acc, 0, 0, 0);
        acc = __builtin_amdgcn_mfma_f32_16x16x32_bf16(AiL[ks], BsH[ks], acc, 0, 0, 0);
      }

#pragma unroll
      for (int r = 0; r < 4; ++r) {
        const int o = ob + cg * 4 + r;
        if (o < kOUT)
          part[(((size_t)kc * kB + b) * kOUT + o) * kC + c] = acc[r];
      }
    }
  }
}

// ---------------------------------------------------------------------------
// Kernel 2: reduce f32 partials, mask, softmax over c, emit split-bf16 attn.
// grid = B*OUT one-wave blocks.
// ---------------------------------------------------------------------------
__global__ __launch_bounds__(64) void sa_softmax(
    const float* __restrict__ part,
    const float* __restrict__ positions,
    const int*   __restrict__ drop_idx,
    unsigned short* __restrict__ a_hi,
    unsigned short* __restrict__ a_lo)
{
  const int bo = blockIdx.x;
  const int b  = bo / kOUT;
  const int o  = bo - b * kOUT;
  const int c  = threadIdx.x;

  float a = 0.f;
#pragma unroll
  for (int fc = 0; fc < kNKC; ++fc)
    a += part[(((size_t)fc * kB + b) * kOUT + o) * kC + c];

  const float2 p  = reinterpret_cast<const float2*>(positions)[b * kC + c];
  const int    di = drop_idx[b];
  const float2 pd = reinterpret_cast<const float2*>(positions)[b * kC + di];
  const float dx = p.x - pd.x;
  const float dy = p.y - pd.y;
  const float d2 = __fadd_rn(__fmul_rn(dx, dx), __fmul_rn(dy, dy));
  if (d2 < 0.1f) a = -1e9f;

  float m = a;
#pragma unroll
  for (int off = 32; off; off >>= 1) m = fmaxf(m, __shfl_xor(m, off));
  const float e = expf(a - m);
  float s = e;
#pragma unroll
  for (int off = 32; off; off >>= 1) s += __shfl_xor(s, off);

  const float att = e / s;
  const unsigned short h = f2bf_rne(att);
  const float res = att - bf2f(h);
  a_hi[((size_t)b * kOUT + o) * kC + c] = h;
  a_lo[((size_t)b * kOUT + o) * kC + c] = f2bf_rne(res);
}

// ---------------------------------------------------------------------------
// Kernel 3: out[b,o,t] = sum_c attn[b,o,c] * X[b,c,t] via bf16 MFMA, split
// precision: Ah*Xh + Ah*Xl + Al*Xh. grid = B*64 blocks (128-t chunk), 256 thr
// = 4 waves; wave owns TWO 16-t n-tiles (shares A-frags), loops 9 M-tiles.
// A staged in LDS XOR-swizzled; X frags from global.
// ---------------------------------------------------------------------------
__global__ __launch_bounds__(256) void sa_apply_mfma(
    const float* __restrict__ X,
    const unsigned short* __restrict__ a_hi,
    const unsigned short* __restrict__ a_lo,
    float* __restrict__ out)
{
  __shared__ unsigned short s_a[2 * 144 * kC];  // hi tile + lo tile, 36 KB

  const int b   = blockIdx.x >> 6;
  const int tc  = blockIdx.x & 63;
  const int t0  = tc * 128;
  const int tid = threadIdx.x;

  // stage A (split) into LDS, swizzled: byte = row*128 + ((ch*16) ^ ((row&7)<<4))
  {
    char* sb = reinterpret_cast<char*>(s_a);
    for (int i = tid; i < 2 * 144 * 8; i += 256) {
      const int tile = (i >= 144 * 8) ? 1 : 0;
      const int r    = (i >> 3) - tile * 144;
      const int ch   = i & 7;
      float4 v;
      if (r < kOUT) {
        const unsigned short* src =
            (tile ? a_lo : a_hi) + ((size_t)b * kOUT + r) * kC + ch * 8;
        v = *reinterpret_cast<const float4*>(src);
      } else {
        v = make_float4(0.f, 0.f, 0.f, 0.f);   // pad rows 129..143
      }
      const int byte = tile * (144 * 128) + r * 128 + ((ch * 16) ^ ((r & 7) << 4));
      *reinterpret_cast<float4*>(sb + byte) = v;
    }
  }

  const int wave = tid >> 6;
  const int lane = tid & 63;
  const int cl   = lane & 15;
  const int cg   = lane >> 4;            // k-group 0..3
  const int tA   = t0 + wave * 32 + cl;  // n-tile A
  const int tB   = tA + 16;              // n-tile B

  // X fragment loads for both n-tiles (global, per-lane strided), split bf16
  const float* Xb = X + (size_t)b * kC * kT;
  float xvA[16], xvB[16];
#pragma unroll
  for (int s2 = 0; s2 < 2; ++s2)
#pragma unroll
    for (int j = 0; j < 8; ++j) {
      const size_t row = (size_t)(s2 * 32 + cg * 8 + j) * kT;
      xvA[s2 * 8 + j] = Xb[row + tA];
      xvB[s2 * 8 + j] = Xb[row + tB];
    }

  bf16x8 XhA0, XlA0, XhA1, XlA1, XhB0, XlB0, XhB1, XlB1;
  split8(xvA,     XhA0, XlA0);
  split8(xvA + 8, XhA1, XlA1);
  split8(xvB,     XhB0, XlB0);
  split8(xvB + 8, XhB1, XlB1);

  __syncthreads();

  const char* sb = reinterpret_cast<const char*>(s_a);
  float* outb = out + (size_t)b * kOUT * kT;

  for (int m = 0; m < 9; ++m) {
    const int row  = m * 16 + cl;
    const int base = row * 128;
    const int sw   = (row & 7) << 4;
    const int gb   = cg * 16;

    const bf16x8 Ah0 = *reinterpret_cast<const bf16x8*>(sb + base + ((gb     ) ^ sw));
    const bf16x8 Ah1 = *reinterpret_cast<const bf16x8*>(sb + base + ((gb + 64) ^ sw));
    const bf16x8 Al0 = *reinterpret_cast<const bf16x8*>(sb + 144 * 128 + base + ((gb     ) ^ sw));
    const bf16x8 Al1 = *reinterpret_cast<const bf16x8*>(sb + 144 * 128 + base + ((gb + 64) ^ sw));

    f32x4 accA = {0.f, 0.f, 0.f, 0.f};
    f32x4 accB = {0.f, 0.f, 0.f, 0.f};
    accA = __builtin_amdgcn_mfma_f32_16x16x32_bf16(Ah0, XhA0, accA, 0, 0, 0);
    accB = __builtin_amdgcn_mfma_f32_16x16x32_bf16(Ah0, XhB0, accB, 0, 0, 0);
    accA = __builtin_amdgcn_mfma_f32_16x16x32_bf16(Ah1, XhA1, accA, 0, 0, 0);
    accB = __builtin_amdgcn_mfma_f32_16x16x32_bf16(Ah1, XhB1, accB, 0, 0, 0);
    accA = __builtin_amdgcn_mfma_f32_16x16x32_bf16(Al0, XhA0, accA, 0, 0, 0);
    accB = __builtin_amdgcn_mfma_f32_16x16x32_bf16(Al0, XhB0, accB, 0, 0, 0);
    accA = __builtin_amdgcn_mfma_f32_16x16x32_bf16(Al1, XhA1, accA, 0, 0, 0);
    accB = __builtin_amdgcn_mfma_f32_16x16x32_bf16(Al1, XhB1, accB, 0, 0, 0);
    accA = __builtin_amdgcn_mfma_f32_16x16x32_bf16(Ah0, XlA0, accA, 0, 0, 0);
    accB = __builtin_amdgcn_mfma_f32_16x16x32_bf16(Ah0, XlB0, accB, 0, 0, 0);
    accA = __builtin_amdgcn_mfma_f32_16x16x32_bf16(Ah1, XlA1, accA, 0, 0, 0);
    accB = __builtin_amdgcn_mfma_f32_16x16x32_bf16(Ah1, XlB1, accB, 0, 0, 0);

#pragma unroll
    for (int r = 0; r < 4; ++r) {
      const int o = m * 16 + cg * 4 + r;
      if (o < kOUT) {
        outb[(size_t)o * kT + tA] = accA[r];
        outb[(size_t)o * kT + tB] = accB[r];
      }
    }
  }
}

// ---------------------------------------------------------------------------
extern "C" void kernel_launch(void* const* d_in, const int* in_sizes, int n_in,
                              void* d_out, int out_size, void* d_ws, size_t ws_size,
                              hipStream_t stream) {
  (void)in_sizes; (void)n_in; (void)out_size; (void)ws_size;
  const float* X         = (const float*)d_in[0];
  const float* positions = (const float*)d_in[1];
  const int*   drop_idx  = (const int*)d_in[2];
  const float* z_real    = (const float*)d_in[3];
  const float* z_imag    = (const float*)d_in[4];
  float* out = (float*)d_out;

  float* part = (float*)d_ws;                                   // [8][32][129][64] f32, 8.45 MB
  unsigned short* ahi = (unsigned short*)(part + (size_t)kNKC * kB * kOUT * kC);
  unsigned short* alo = ahi + (size_t)kB * kOUT * kC;           // bf16, 528 KB each

  sa_phase_mfma<<<kB * kNKC * 2, 256, 0, stream>>>(positions, z_real, z_imag, part);
  sa_softmax<<<kB * kOUT, 64, 0, stream>>>(part, positions, drop_idx, ahi, alo);
  sa_apply_mfma<<<kB * 64, 256, 0, stream>>>(X, ahi, alo, out);
}

// Round 7
// 235.490 us; speedup vs baseline: 1.0487x; 1.0487x over previous
//
#include <hip/hip_runtime.h>
#include <math.h>

typedef __bf16 bf16x8 __attribute__((ext_vector_type(8)));
typedef unsigned short u16x8 __attribute__((ext_vector_type(8)));
typedef float f32x4 __attribute__((ext_vector_type(4)));

namespace {
constexpr int kB   = 32;
constexpr int kC   = 64;
constexpr int kT   = 8192;
constexpr int kOUT = 129;
constexpr int kKK  = 1024;   // K*K
constexpr int kNKC = 8;      // k-chunks in phase GEMM (128 f each)
constexpr int kOP  = 144;    // o rows padded to 144 (9 m-tiles, guard-free loads)
}

__device__ inline float sin2pi(float r) {  // r in revolutions, [0,1)
  float o; asm("v_sin_f32 %0, %1" : "=v"(o) : "v"(r)); return o;
}
__device__ inline float cos2pi(float r) {
  float o; asm("v_cos_f32 %0, %1" : "=v"(o) : "v"(r)); return o;
}
__device__ inline unsigned short f2bf_rne(float f) {
  unsigned int u = __builtin_bit_cast(unsigned int, f);
  return (unsigned short)((u + 0x7fffu + ((u >> 16) & 1u)) >> 16);
}
__device__ inline float bf2f(unsigned short h) {
  return __builtin_bit_cast(float, (unsigned int)h << 16);
}
__device__ inline void split8(const float* v, bf16x8& hi, bf16x8& lo) {
  u16x8 h, l;
#pragma unroll
  for (int j = 0; j < 8; ++j) {
    const unsigned short hh = f2bf_rne(v[j]);
    h[j] = hh;
    l[j] = f2bf_rne(v[j] - bf2f(hh));
  }
  hi = __builtin_bit_cast(bf16x8, h);
  lo = __builtin_bit_cast(bf16x8, l);
}
__device__ inline bf16x8 ldbf8(const unsigned short* p) {
  return __builtin_bit_cast(bf16x8, *reinterpret_cast<const u16x8*>(p));
}

// ---------------------------------------------------------------------------
// K0z: split z -> bf16 hi/lo, layout [fb=0..127][o=0..143][fj=0..7]
// (o padded with zeros so the phase GEMM needs no row guards). 147456 elems.
// ---------------------------------------------------------------------------
__global__ __launch_bounds__(256) void sa_split_z(
    const float* __restrict__ z_real, const float* __restrict__ z_imag,
    unsigned short* __restrict__ zrh, unsigned short* __restrict__ zrl,
    unsigned short* __restrict__ zih, unsigned short* __restrict__ zil)
{
  const int i = blockIdx.x * 256 + threadIdx.x;
  if (i >= 128 * kOP * 8) return;
  const int fj = i & 7;
  const int o  = (i >> 3) % kOP;
  const int fb = i / (kOP * 8);
  const int f  = fb * 8 + fj;
  float vr = 0.f, vi = 0.f;
  if (o < kOUT) {
    vr = z_real[(size_t)o * kKK + f];
    vi = z_imag[(size_t)o * kKK + f];
  }
  unsigned short h = f2bf_rne(vr);
  zrh[i] = h; zrl[i] = f2bf_rne(vr - bf2f(h));
  h = f2bf_rne(vi);
  zih[i] = h; zil[i] = f2bf_rne(vi - bf2f(h));
}

// ---------------------------------------------------------------------------
// K0c: materialize split-bf16 cis tables, layout [b][fb=0..127][c=0..63][fj].
// One trig + split per (b,c,f); 2.1M threads, coalesced 2B stores.
// ---------------------------------------------------------------------------
__global__ __launch_bounds__(256) void sa_cis(
    const float* __restrict__ positions,
    unsigned short* __restrict__ csh, unsigned short* __restrict__ csl,
    unsigned short* __restrict__ snh, unsigned short* __restrict__ snl)
{
  const int i = blockIdx.x * 256 + threadIdx.x;   // < 32*128*64*8 = 2097152
  const int fj = i & 7;
  const int c  = (i >> 3) & 63;
  const int fb = (i >> 9) & 127;
  const int b  = i >> 16;
  const int f  = fb * 8 + fj;
  const float2 p = reinterpret_cast<const float2*>(positions)[b * kC + c];
  const float kf = (float)((f & 31) + 1);   // coef_k = (f % 32) + 1
  const float lf = (float)((f >> 5) + 1);   // coef_l = (f / 32) + 1
  // match reference rounding: fl(fl(x*k) + fl(y*l)); trig in revolutions
  const float w = __fadd_rn(__fmul_rn(p.x, kf), __fmul_rn(p.y, lf));
  const float r = w - floorf(w);
  const float cs = cos2pi(r);
  const float sn = sin2pi(r);
  unsigned short h = f2bf_rne(cs);
  csh[i] = h; csl[i] = f2bf_rne(cs - bf2f(h));
  h = f2bf_rne(sn);
  snh[i] = h; snl[i] = f2bf_rne(sn - bf2f(h));
}

// ---------------------------------------------------------------------------
// K1: part[kc][b][o][c] = sum_{f in chunk} z[o,f]*cis[f,c] -- pure bf16 MFMA
// (split hi/lo both operands, lo*lo dropped). All operands preprocessed; the
// loop is loads + 120 MFMA, no trig, no splits, no guards on loads.
// Grid = 32b x 8kc x 2mh = 512 blocks x 256 thr; wave w owns c-tile w*16.
// MFMA map (HW-verified r4): A row=lane&15,k=8*(lane>>4)+j; B col=lane&15;
// D col=lane&15,row=(lane>>4)*4+r.
// ---------------------------------------------------------------------------
__global__ __launch_bounds__(256) void sa_phase_gemm(
    const unsigned short* __restrict__ zrh, const unsigned short* __restrict__ zrl,
    const unsigned short* __restrict__ zih, const unsigned short* __restrict__ zil,
    const unsigned short* __restrict__ csh, const unsigned short* __restrict__ csl,
    const unsigned short* __restrict__ snh, const unsigned short* __restrict__ snl,
    float* __restrict__ part)
{
  const int bid = blockIdx.x;
  const int b   = bid & 31;
  const int kc  = (bid >> 5) & 7;
  const int mh  = bid >> 8;            // 0: m-tiles 0..4, 1: m-tiles 5..8
  const int w    = threadIdx.x >> 6;
  const int lane = threadIdx.x & 63;
  const int cg   = lane >> 4;
  const int cl   = lane & 15;
  const int c    = w * 16 + cl;

  // B-frags (cis) for 4 k-steps
  bf16x8 BcH[4], BcL[4], BsH[4], BsL[4];
#pragma unroll
  for (int ks = 0; ks < 4; ++ks) {
    const size_t off = ((size_t)(b * 128 + kc * 16 + ks * 4 + cg) * kC + c) * 8;
    BcH[ks] = ldbf8(csh + off);
    BcL[ks] = ldbf8(csl + off);
    BsH[ks] = ldbf8(snh + off);
    BsL[ks] = ldbf8(snl + off);
  }

  const int nm  = mh ? 4 : 5;
  const int ob0 = mh * 80;

#pragma unroll
  for (int m = 0; m < 5; ++m) {
    if (m < nm) {
      const int ob = ob0 + m * 16;
      const int oa = ob + cl;          // padded rows -> no guard
      f32x4 acc = {0.f, 0.f, 0.f, 0.f};
#pragma unroll
      for (int ks = 0; ks < 4; ++ks) {
        const size_t zo = ((size_t)(kc * 16 + ks * 4 + cg) * kOP + oa) * 8;
        const bf16x8 ArH = ldbf8(zrh + zo);
        const bf16x8 ArL = ldbf8(zrl + zo);
        const bf16x8 AiH = ldbf8(zih + zo);
        const bf16x8 AiL = ldbf8(zil + zo);
        acc = __builtin_amdgcn_mfma_f32_16x16x32_bf16(ArH, BcH[ks], acc, 0, 0, 0);
        acc = __builtin_amdgcn_mfma_f32_16x16x32_bf16(ArH, BcL[ks], acc, 0, 0, 0);
        acc = __builtin_amdgcn_mfma_f32_16x16x32_bf16(ArL, BcH[ks], acc, 0, 0, 0);
        acc = __builtin_amdgcn_mfma_f32_16x16x32_bf16(AiH, BsH[ks], acc, 0, 0, 0);
        acc = __builtin_amdgcn_mfma_f32_16x16x32_bf16(AiH, BsL[ks], acc, 0, 0, 0);
        acc = __builtin_amdgcn_mfma_f32_16x16x32_bf16(AiL, BsH[ks], acc, 0, 0, 0);
      }
#pragma unroll
      for (int r = 0; r < 4; ++r) {
        const int o = ob + cg * 4 + r;
        if (o < kOUT)
          part[(((size_t)kc * kB + b) * kOUT + o) * kC + c] = acc[r];
      }
    }
  }
}

// ---------------------------------------------------------------------------
// K2: reduce f32 partials, mask, softmax over c, emit split-bf16 attn.
// 256-thr blocks, one wave per (b,o).
// ---------------------------------------------------------------------------
__global__ __launch_bounds__(256) void sa_softmax(
    const float* __restrict__ part,
    const float* __restrict__ positions,
    const int*   __restrict__ drop_idx,
    unsigned short* __restrict__ a_hi,
    unsigned short* __restrict__ a_lo)
{
  const int bo = blockIdx.x * 4 + (threadIdx.x >> 6);
  if (bo >= kB * kOUT) return;
  const int b = bo / kOUT;
  const int o = bo - b * kOUT;
  const int c = threadIdx.x & 63;

  float a = 0.f;
#pragma unroll
  for (int fc = 0; fc < kNKC; ++fc)
    a += part[(((size_t)fc * kB + b) * kOUT + o) * kC + c];

  const float2 p  = reinterpret_cast<const float2*>(positions)[b * kC + c];
  const int    di = drop_idx[b];
  const float2 pd = reinterpret_cast<const float2*>(positions)[b * kC + di];
  const float dx = p.x - pd.x;
  const float dy = p.y - pd.y;
  const float d2 = __fadd_rn(__fmul_rn(dx, dx), __fmul_rn(dy, dy));
  if (d2 < 0.1f) a = -1e9f;

  float m = a;
#pragma unroll
  for (int off = 32; off; off >>= 1) m = fmaxf(m, __shfl_xor(m, off));
  const float e = expf(a - m);
  float s = e;
#pragma unroll
  for (int off = 32; off; off >>= 1) s += __shfl_xor(s, off);

  const float att = e / s;
  const unsigned short h = f2bf_rne(att);
  a_hi[(size_t)bo * kC + c] = h;
  a_lo[(size_t)bo * kC + c] = f2bf_rne(att - bf2f(h));
}

// ---------------------------------------------------------------------------
// K3: out[b,o,t] = sum_c attn[b,o,c] * X[b,c,t] via bf16 MFMA (Ah*Xh + Ah*Xl
// + Al*Xh). Grid = 32b x 32tc (256-t chunk) = 1024 blocks x 4 waves; each
// wave owns FOUR 16-t n-tiles (A-frag reads amortized 4x), 9 M-tiles.
// A staged in LDS XOR-swizzled.
// ---------------------------------------------------------------------------
__global__ __launch_bounds__(256) void sa_apply_mfma(
    const float* __restrict__ X,
    const unsigned short* __restrict__ a_hi,
    const unsigned short* __restrict__ a_lo,
    float* __restrict__ out)
{
  __shared__ unsigned short s_a[2 * 144 * kC];  // hi + lo tile, 36 KB

  const int b   = blockIdx.x >> 5;
  const int tc  = blockIdx.x & 31;
  const int t0  = tc * 256;
  const int tid = threadIdx.x;

  // stage split attn[b] into LDS, swizzled: byte = row*128 + ((ch*16)^((row&7)<<4))
  {
    char* sb = reinterpret_cast<char*>(s_a);
    for (int i = tid; i < 2 * 144 * 8; i += 256) {
      const int tile = (i >= 144 * 8) ? 1 : 0;
      const int r    = (i >> 3) - tile * 144;
      const int ch   = i & 7;
      float4 v;
      if (r < kOUT) {
        const unsigned short* src =
            (tile ? a_lo : a_hi) + ((size_t)b * kOUT + r) * kC + ch * 8;
        v = *reinterpret_cast<const float4*>(src);
      } else {
        v = make_float4(0.f, 0.f, 0.f, 0.f);
      }
      const int byte = tile * (144 * 128) + r * 128 + ((ch * 16) ^ ((r & 7) << 4));
      *reinterpret_cast<float4*>(sb + byte) = v;
    }
  }

  const int wave = tid >> 6;
  const int lane = tid & 63;
  const int cl   = lane & 15;
  const int cg   = lane >> 4;            // k-group 0..3
  const int tb   = t0 + wave * 64;       // wave's 64-t range

  // X frags for 4 n-tiles, split bf16
  const float* Xb = X + (size_t)b * kC * kT;
  bf16x8 Xh[4][2], Xl[4][2];
#pragma unroll
  for (int n = 0; n < 4; ++n) {
    const int t = tb + n * 16 + cl;
    float xv[16];
#pragma unroll
    for (int s2 = 0; s2 < 2; ++s2)
#pragma unroll
      for (int j = 0; j < 8; ++j)
        xv[s2 * 8 + j] = Xb[(size_t)(s2 * 32 + cg * 8 + j) * kT + t];
    split8(xv,     Xh[n][0], Xl[n][0]);
    split8(xv + 8, Xh[n][1], Xl[n][1]);
  }

  __syncthreads();

  const char* sb = reinterpret_cast<const char*>(s_a);
  float* outb = out + (size_t)b * kOUT * kT;

  for (int m = 0; m < 9; ++m) {
    const int row  = m * 16 + cl;
    const int base = row * 128;
    const int sw   = (row & 7) << 4;
    const int gb   = cg * 16;

    const bf16x8 Ah0 = *reinterpret_cast<const bf16x8*>(sb + base + ((gb     ) ^ sw));
    const bf16x8 Ah1 = *reinterpret_cast<const bf16x8*>(sb + base + ((gb + 64) ^ sw));
    const bf16x8 Al0 = *reinterpret_cast<const bf16x8*>(sb + 144 * 128 + base + ((gb     ) ^ sw));
    const bf16x8 Al1 = *reinterpret_cast<const bf16x8*>(sb + 144 * 128 + base + ((gb + 64) ^ sw));

    f32x4 acc[4];
#pragma unroll
    for (int n = 0; n < 4; ++n) {
      acc[n] = f32x4{0.f, 0.f, 0.f, 0.f};
      acc[n] = __builtin_amdgcn_mfma_f32_16x16x32_bf16(Ah0, Xh[n][0], acc[n], 0, 0, 0);
      acc[n] = __builtin_amdgcn_mfma_f32_16x16x32_bf16(Ah1, Xh[n][1], acc[n], 0, 0, 0);
      acc[n] = __builtin_amdgcn_mfma_f32_16x16x32_bf16(Al0, Xh[n][0], acc[n], 0, 0, 0);
      acc[n] = __builtin_amdgcn_mfma_f32_16x16x32_bf16(Al1, Xh[n][1], acc[n], 0, 0, 0);
      acc[n] = __builtin_amdgcn_mfma_f32_16x16x32_bf16(Ah0, Xl[n][0], acc[n], 0, 0, 0);
      acc[n] = __builtin_amdgcn_mfma_f32_16x16x32_bf16(Ah1, Xl[n][1], acc[n], 0, 0, 0);
    }

#pragma unroll
    for (int n = 0; n < 4; ++n)
#pragma unroll
      for (int r = 0; r < 4; ++r) {
        const int o = m * 16 + cg * 4 + r;
        if (o < kOUT)
          outb[(size_t)o * kT + tb + n * 16 + cl] = acc[n][r];
      }
  }
}

// ---------------------------------------------------------------------------
extern "C" void kernel_launch(void* const* d_in, const int* in_sizes, int n_in,
                              void* d_out, int out_size, void* d_ws, size_t ws_size,
                              hipStream_t stream) {
  (void)in_sizes; (void)n_in; (void)out_size; (void)ws_size;
  const float* X         = (const float*)d_in[0];
  const float* positions = (const float*)d_in[1];
  const int*   drop_idx  = (const int*)d_in[2];
  const float* z_real    = (const float*)d_in[3];
  const float* z_imag    = (const float*)d_in[4];
  float* out = (float*)d_out;

  // workspace layout (~27.5 MB of ~540 MB)
  char* wsb = (char*)d_ws;
  float* part = (float*)wsb;                                    // 8,454,144 B
  unsigned short* ahi = (unsigned short*)(wsb + 8454144);       // 528,384 B
  unsigned short* alo = ahi + 264192;                           // 528,384 B
  unsigned short* zrh = alo + 264192;                           // 4 x 294,912 B
  unsigned short* zrl = zrh + 147456;
  unsigned short* zih = zrl + 147456;
  unsigned short* zil = zih + 147456;
  unsigned short* csh = zil + 147456;                           // 4 x 4,194,304 B
  unsigned short* csl = csh + 2097152;
  unsigned short* snh = csl + 2097152;
  unsigned short* snl = snh + 2097152;

  sa_split_z<<<576, 256, 0, stream>>>(z_real, z_imag, zrh, zrl, zih, zil);
  sa_cis<<<8192, 256, 0, stream>>>(positions, csh, csl, snh, snl);
  sa_phase_gemm<<<kB * kNKC * 2, 256, 0, stream>>>(zrh, zrl, zih, zil,
                                                   csh, csl, snh, snl, part);
  sa_softmax<<<(kB * kOUT + 3) / 4, 256, 0, stream>>>(part, positions, drop_idx, ahi, alo);
  sa_apply_mfma<<<kB * 32, 256, 0, stream>>>(X, ahi, alo, out);
}